// Round 10
// baseline (301.505 us; speedup 1.0000x reference)
//
#include <hip/hip_runtime.h>
#include <stdint.h>

#define N_NODES 50000
#define N_EDGES 800000
#define DIM 64
#define FEAT_TOTAL (N_NODES * DIM)
#define ELL_S 48   // max degree bound; P(Poisson(16) >= 48) ~ 5e-11, guarded
#define NB 200     // coarse buckets (col / 250)
#define BROWS 250  // nodes per bucket
#define BCAP 6000  // bucket capacity; mean 4000, sd ~63 -> +31 sd, guarded
#define ECHUNK (N_EDGES / NB)  // 4000 edges per phaseA block
#define AST 200    // LDS row stride in bf16 (192 + 8 pad -> 2-way banks, free)

typedef __attribute__((ext_vector_type(8))) short bf16x8;
typedef __attribute__((ext_vector_type(4))) float f32x4;

// ---------------------------------------------------------------------------
// bf16 storage helpers (accumulate fp32, store bf16 RNE)
// ---------------------------------------------------------------------------
__device__ inline float bf2f(uint32_t h) { return __uint_as_float(h << 16); }
__device__ inline uint32_t f2bf(float f) {
  uint32_t u = __float_as_uint(f);
  return (u + 0x7fffu + ((u >> 16) & 1u)) >> 16;
}

// ---------------------------------------------------------------------------
// Threefry-2x32, 20 rounds — JAX-exact (validated R2: partitionable layout).
// ---------------------------------------------------------------------------
__host__ __device__ inline void threefry2x32(uint32_t k0, uint32_t k1,
                                             uint32_t x0, uint32_t x1,
                                             uint32_t& o0, uint32_t& o1) {
  uint32_t ks[3] = {k0, k1, k0 ^ k1 ^ 0x1BD11BDAu};
  x0 += ks[0];
  x1 += ks[1];
  const uint32_t R[2][4] = {{13u, 15u, 26u, 6u}, {17u, 29u, 16u, 24u}};
#pragma unroll
  for (int g = 0; g < 5; ++g) {
    const uint32_t* r = R[g & 1];
#pragma unroll
    for (int j = 0; j < 4; ++j) {
      x0 += x1;
      x1 = (x1 << r[j]) | (x1 >> (32u - r[j]));
      x1 ^= x0;
    }
    x0 += ks[(g + 1) % 3];
    x1 += ks[(g + 2) % 3] + (uint32_t)(g + 1);
  }
  o0 = x0;
  o1 = x1;
}

// ===========================================================================
// Phase A: coarse-bucket edges by col/BROWS. LDS histogram -> one global
// atomic per (block,bucket); contiguous run writes into fixed-cap buckets.
// entry = { row | col_local<<17 , w } (row<2^17, col_local<2^8).
// ===========================================================================
__global__ __launch_bounds__(256) void phaseA(
    const int* __restrict__ row, const int* __restrict__ col,
    const float* __restrict__ w, int* __restrict__ bfill,
    int2* __restrict__ bkt, int E) {
  __shared__ int hist[NB], base[NB], off[NB];
  int t = threadIdx.x;
  int lo = blockIdx.x * ECHUNK;
  int hi = min(lo + ECHUNK, E);
  for (int i = t; i < NB; i += 256) hist[i] = 0;
  __syncthreads();
  for (int e = lo + t; e < hi; e += 256) atomicAdd(&hist[col[e] / BROWS], 1);
  __syncthreads();
  for (int i = t; i < NB; i += 256) {
    base[i] = atomicAdd(&bfill[i], hist[i]);
    off[i] = 0;
  }
  __syncthreads();
  for (int e = lo + t; e < hi; e += 256) {
    int c = col[e];
    int bin = c / BROWS;
    int rank = atomicAdd(&off[bin], 1);
    int dest = base[bin] + rank;
    if (dest < BCAP) {
      int2 ent;
      ent.x = row[e] | ((c - bin * BROWS) << 17);
      ent.y = __float_as_int(w[e]);
      bkt[(size_t)bin * BCAP + dest] = ent;
    }
  }
}

// ===========================================================================
// Phase C: one block per bucket; ELL rows L2-resident -> stores combine.
// LDS atomics assign slots + accumulate deg; dinv computed in-block (bucket
// owns ALL edges into its 250 nodes, so deg is complete here).
// ===========================================================================
__global__ __launch_bounds__(256) void phaseC(
    const int* __restrict__ bfill, const int2* __restrict__ bkt,
    int2* __restrict__ ell, int* __restrict__ cnt, float* __restrict__ dinv) {
  __shared__ int lcnt[BROWS];
  __shared__ float ldeg[BROWS];
  int t = threadIdx.x;
  int b = blockIdx.x;
  for (int i = t; i < BROWS; i += 256) {
    lcnt[i] = 0;
    ldeg[i] = 0.0f;
  }
  __syncthreads();
  int sz = min(bfill[b], BCAP);
  const int2* src = bkt + (size_t)b * BCAP;
  for (int i = t; i < sz; i += 256) {
    int2 ent = src[i];
    int cl = (ent.x >> 17) & 0xff;
    int r = ent.x & 0x1ffff;
    float wv = __int_as_float(ent.y);
    int slot = atomicAdd(&lcnt[cl], 1);
    if (slot < ELL_S) {
      int2 o;
      o.x = r;
      o.y = ent.y;
      ell[(size_t)(b * BROWS + cl) * ELL_S + slot] = o;
    }
    atomicAdd(&ldeg[cl], wv);
  }
  __syncthreads();
  for (int i = t; i < BROWS; i += 256) {
    cnt[b * BROWS + i] = lcnt[i];
    float d = ldeg[i];
    dinv[b * BROWS + i] = (d > 0.0f) ? rsqrtf(fmaxf(d, 1e-12f)) : 0.0f;
  }
}

// wave per node, lane per slot: weight <- dinv[src]*w*dinv[dst]
__global__ void normw_ell(int2* __restrict__ ell, const int* __restrict__ cnt,
                          const float* __restrict__ dinv, int n_nodes) {
  int gid = blockIdx.x * blockDim.x + threadIdx.x;
  int n = gid >> 6;
  if (n >= n_nodes) return;
  int lane = threadIdx.x & 63;
  int c = min(cnt[n], ELL_S);
  if (lane >= c) return;
  float dn = dinv[n];
  int2 ent = ell[(size_t)n * ELL_S + lane];
  ent.y = __float_as_int(dinv[ent.x] * __int_as_float(ent.y) * dn);
  ell[(size_t)n * ELL_S + lane] = ent;
}

// Conversions: x -> bf16 xb; W0/W1 (fp32 [192][64] k-major) -> bf16 [64][192]
__global__ void cvt_all(const float* __restrict__ x,
                        const float* __restrict__ W0,
                        const float* __restrict__ W1,
                        uint16_t* __restrict__ xb, uint16_t* __restrict__ Wt0,
                        uint16_t* __restrict__ Wt1) {
  int id = blockIdx.x * blockDim.x + threadIdx.x;
  if (id < FEAT_TOTAL) xb[id] = (uint16_t)f2bf(x[id]);
  if (id < 192 * DIM) {
    int kk = id >> 6;
    int j = id & 63;
    Wt0[j * 192 + kk] = (uint16_t)f2bf(W0[id]);
    Wt1[j * 192 + kk] = (uint16_t)f2bf(W1[id]);
  }
}

// ===========================================================================
// Propagate bf16: TWO nodes per wave (32 lanes each); per half:
// eg 0..3, fc 0..7 (uint4 = 8 bf16); unroll2 -> 8 chains/node, 16/wave.
// ===========================================================================
__global__ void prop_bf16(const uint16_t* __restrict__ src,
                          uint16_t* __restrict__ dst,
                          const int2* __restrict__ ell,
                          const int* __restrict__ cnt, int n_nodes) {
  int gid = blockIdx.x * blockDim.x + threadIdx.x;
  int n = gid >> 5;  // node per 32-lane half
  if (n >= n_nodes) return;
  int hl = threadIdx.x & 31;
  int eg = hl >> 3;  // 0..3
  int fc = hl & 7;   // 0..7, 8 bf16 each
  int c = min(cnt[n], ELL_S);
  const int2* p = ell + (size_t)n * ELL_S;
  float acc[8] = {0.f, 0.f, 0.f, 0.f, 0.f, 0.f, 0.f, 0.f};
  int k = eg;
  for (; k + 4 < c; k += 8) {
    int2 e0 = p[k];
    int2 e1 = p[k + 4];
    float w0 = __int_as_float(e0.y);
    float w1 = __int_as_float(e1.y);
    uint4 v0 = *(const uint4*)&src[e0.x * DIM + fc * 8];
    uint4 v1 = *(const uint4*)&src[e1.x * DIM + fc * 8];
    acc[0] += bf2f(v0.x & 0xffffu) * w0 + bf2f(v1.x & 0xffffu) * w1;
    acc[1] += bf2f(v0.x >> 16) * w0 + bf2f(v1.x >> 16) * w1;
    acc[2] += bf2f(v0.y & 0xffffu) * w0 + bf2f(v1.y & 0xffffu) * w1;
    acc[3] += bf2f(v0.y >> 16) * w0 + bf2f(v1.y >> 16) * w1;
    acc[4] += bf2f(v0.z & 0xffffu) * w0 + bf2f(v1.z & 0xffffu) * w1;
    acc[5] += bf2f(v0.z >> 16) * w0 + bf2f(v1.z >> 16) * w1;
    acc[6] += bf2f(v0.w & 0xffffu) * w0 + bf2f(v1.w & 0xffffu) * w1;
    acc[7] += bf2f(v0.w >> 16) * w0 + bf2f(v1.w >> 16) * w1;
  }
  if (k < c) {
    int2 e0 = p[k];
    float w0 = __int_as_float(e0.y);
    uint4 v0 = *(const uint4*)&src[e0.x * DIM + fc * 8];
    acc[0] += bf2f(v0.x & 0xffffu) * w0;
    acc[1] += bf2f(v0.x >> 16) * w0;
    acc[2] += bf2f(v0.y & 0xffffu) * w0;
    acc[3] += bf2f(v0.y >> 16) * w0;
    acc[4] += bf2f(v0.z & 0xffffu) * w0;
    acc[5] += bf2f(v0.z >> 16) * w0;
    acc[6] += bf2f(v0.w & 0xffffu) * w0;
    acc[7] += bf2f(v0.w >> 16) * w0;
  }
#pragma unroll
  for (int m = 8; m <= 16; m <<= 1) {
#pragma unroll
    for (int j = 0; j < 8; ++j) acc[j] += __shfl_xor(acc[j], m);
  }
  if (eg == 0) {
    uint4 r;
    r.x = f2bf(acc[0]) | (f2bf(acc[1]) << 16);
    r.y = f2bf(acc[2]) | (f2bf(acc[3]) << 16);
    r.z = f2bf(acc[4]) | (f2bf(acc[5]) << 16);
    r.w = f2bf(acc[6]) | (f2bf(acc[7]) << 16);
    *(uint4*)&dst[(size_t)n * DIM + fc * 8] = r;
  }
}

__global__ void sprop_add_ell(const float* __restrict__ src,
                              const float* __restrict__ addv,
                              float* __restrict__ dst,
                              const int2* __restrict__ ell,
                              const int* __restrict__ cnt, int n_nodes) {
  int n = blockIdx.x * blockDim.x + threadIdx.x;
  if (n >= n_nodes) return;
  int c = min(cnt[n], ELL_S);
  const int2* p = ell + (size_t)n * ELL_S;
  float acc = addv[n];
  for (int k = 0; k < c; ++k)
    acc += __int_as_float(p[k].y) * src[p[k].x];
  dst[n] = acc;
}

// ===========================================================================
// Fused hop-2 + gemm3 via MFMA 16x16x32 bf16. Block = 64 dst rows x 64 cols.
// sA cols 0..63 = X rows (own), 64..127 = P1 rows (own),
// 128..191 = P2 rows gathered on the fly from P1 via ELL (used-once fusion).
// Wave w = col-tile w; 6 B-frags + 24 A-frags + 24 MFMA.
// Layouts (m89/m120 verified): A[m=lane&15][k=quad*8+j]; B[n=lane&15][k];
// C/D col=lane&15, row=quad*4+reg. Epilogue: threefry dropout + PReLU.
// In-place safe (out==X): block stages/gathers before writing; the gather
// source is P1 (never out).
// ===========================================================================
__global__ __launch_bounds__(256) void gemm3_mfma_g(
    const uint16_t* X, const uint16_t* __restrict__ P1,
    const int2* __restrict__ ell, const int* __restrict__ cnt,
    const uint16_t* __restrict__ Wt, uint16_t* out, int n_nodes, uint32_t k0,
    uint32_t k1, const float* __restrict__ a) {
  __shared__ uint16_t sA[64 * AST];  // 25600 B
  __shared__ uint16_t sB[64 * AST];  // 25600 B
  int t = threadIdx.x;
  int n0 = blockIdx.x * 64;
  // ---- stage X (cols 0..63) and P1 (cols 64..127), own rows ----
#pragma unroll
  for (int m = 0; m < 2; ++m) {
    const uint16_t* S = (m == 0) ? X : P1;
#pragma unroll
    for (int it = 0; it < 2; ++it) {
      int chunk = t + it * 256;  // 64 rows x 8 uint4-chunks
      int rrow = chunk >> 3;
      int cc = chunk & 7;
      int nc = min(n0 + rrow, n_nodes - 1);
      uint4 v = *(const uint4*)&S[(size_t)nc * DIM + cc * 8];
      *(uint4*)&sA[rrow * AST + m * DIM + cc * 8] = v;
    }
  }
  // ---- gather-stage P2 rows (cols 128..191): P2[n] = sum w * P1[idx] ----
  {
    int wv = t >> 6;
    int lane = t & 63;
    int half = lane >> 5;  // 0..1
    int hl = lane & 31;
    int eg = hl >> 3;  // 0..3
    int fc = hl & 7;   // 0..7
#pragma unroll
    for (int i = 0; i < 8; ++i) {
      int ln = wv * 16 + i * 2 + half;  // 0..63 local row
      int nc = min(n0 + ln, n_nodes - 1);
      int c = min(cnt[nc], ELL_S);
      const int2* p = ell + (size_t)nc * ELL_S;
      float acc[8] = {0.f, 0.f, 0.f, 0.f, 0.f, 0.f, 0.f, 0.f};
      int k = eg;
      for (; k + 4 < c; k += 8) {
        int2 e0 = p[k];
        int2 e1 = p[k + 4];
        float w0 = __int_as_float(e0.y);
        float w1 = __int_as_float(e1.y);
        uint4 v0 = *(const uint4*)&P1[e0.x * DIM + fc * 8];
        uint4 v1 = *(const uint4*)&P1[e1.x * DIM + fc * 8];
        acc[0] += bf2f(v0.x & 0xffffu) * w0 + bf2f(v1.x & 0xffffu) * w1;
        acc[1] += bf2f(v0.x >> 16) * w0 + bf2f(v1.x >> 16) * w1;
        acc[2] += bf2f(v0.y & 0xffffu) * w0 + bf2f(v1.y & 0xffffu) * w1;
        acc[3] += bf2f(v0.y >> 16) * w0 + bf2f(v1.y >> 16) * w1;
        acc[4] += bf2f(v0.z & 0xffffu) * w0 + bf2f(v1.z & 0xffffu) * w1;
        acc[5] += bf2f(v0.z >> 16) * w0 + bf2f(v1.z >> 16) * w1;
        acc[6] += bf2f(v0.w & 0xffffu) * w0 + bf2f(v1.w & 0xffffu) * w1;
        acc[7] += bf2f(v0.w >> 16) * w0 + bf2f(v1.w >> 16) * w1;
      }
      if (k < c) {
        int2 e0 = p[k];
        float w0 = __int_as_float(e0.y);
        uint4 v0 = *(const uint4*)&P1[e0.x * DIM + fc * 8];
        acc[0] += bf2f(v0.x & 0xffffu) * w0;
        acc[1] += bf2f(v0.x >> 16) * w0;
        acc[2] += bf2f(v0.y & 0xffffu) * w0;
        acc[3] += bf2f(v0.y >> 16) * w0;
        acc[4] += bf2f(v0.z & 0xffffu) * w0;
        acc[5] += bf2f(v0.z >> 16) * w0;
        acc[6] += bf2f(v0.w & 0xffffu) * w0;
        acc[7] += bf2f(v0.w >> 16) * w0;
      }
#pragma unroll
      for (int m = 8; m <= 16; m <<= 1) {
#pragma unroll
        for (int j = 0; j < 8; ++j) acc[j] += __shfl_xor(acc[j], m);
      }
      if (eg == 0) {
        uint4 r;
        r.x = f2bf(acc[0]) | (f2bf(acc[1]) << 16);
        r.y = f2bf(acc[2]) | (f2bf(acc[3]) << 16);
        r.z = f2bf(acc[4]) | (f2bf(acc[5]) << 16);
        r.w = f2bf(acc[6]) | (f2bf(acc[7]) << 16);
        *(uint4*)&sA[ln * AST + 2 * DIM + fc * 8] = r;
      }
    }
  }
  // ---- stage B: Wt [64][192] -> sB padded (L2-resident source) ----
#pragma unroll
  for (int it = 0; it < 6; ++it) {
    int chunk = t + it * 256;  // 64 rows x 24 uint4-chunks
    int rrow = chunk / 24;
    int cc = chunk % 24;
    uint4 v = *(const uint4*)&Wt[rrow * 192 + cc * 8];
    *(uint4*)&sB[rrow * AST + cc * 8] = v;
  }
  __syncthreads();
  int wv = t >> 6;  // wave id = col-tile
  int lane = t & 63;
  int lm = lane & 15;
  int quad = lane >> 4;
  f32x4 acc[4] = {};  // row-tiles 0..3
  const uint16_t* pB = &sB[(wv * 16 + lm) * AST + quad * 8];
  const uint16_t* pA = &sA[lm * AST + quad * 8];
#pragma unroll
  for (int ks = 0; ks < 6; ++ks) {
    bf16x8 bf = *(const bf16x8*)(pB + ks * 32);
#pragma unroll
    for (int rt = 0; rt < 4; ++rt) {
      bf16x8 af = *(const bf16x8*)(pA + rt * 16 * AST + ks * 32);
      acc[rt] = __builtin_amdgcn_mfma_f32_16x16x32_bf16(af, bf, acc[rt], 0, 0, 0);
    }
  }
  // ---- epilogue: dropout (JAX threefry) + PReLU, bf16 store ----
  float al = a[0];
  int col = wv * 16 + lm;
#pragma unroll
  for (int rt = 0; rt < 4; ++rt) {
#pragma unroll
    for (int r = 0; r < 4; ++r) {
      int n = n0 + rt * 16 + quad * 4 + r;
      if (n < n_nodes) {
        float v = acc[rt][r];
        uint32_t idx = (uint32_t)(n * DIM + col);
        uint32_t o0, o1;
        threefry2x32(k0, k1, 0u, idx, o0, o1);
        v = ((o0 ^ o1) & 0x80000000u) ? 0.0f : (v + v);  // dropout p=0.5
        v = (v >= 0.0f) ? v : al * v;                     // PReLU
        out[(size_t)n * DIM + col] = (uint16_t)f2bf(v);
      }
    }
  }
}

// Layer-2 matvecs from bf16 F: y_k[n] = sum_i F[n][i]*W2[k][i][0]
__global__ void matvec3_bf16(const uint16_t* __restrict__ F,
                             const float* __restrict__ W2,
                             float* __restrict__ y0, float* __restrict__ y1,
                             float* __restrict__ y2, int n_nodes) {
  int gid = blockIdx.x * blockDim.x + threadIdx.x;
  int n = gid >> 6;
  int i = gid & 63;
  if (n >= n_nodes) return;
  float v = bf2f((uint32_t)F[(size_t)n * DIM + i]);
  float s0 = v * W2[i], s1 = v * W2[DIM + i], s2 = v * W2[2 * DIM + i];
#pragma unroll
  for (int off = 32; off > 0; off >>= 1) {
    s0 += __shfl_down(s0, off);
    s1 += __shfl_down(s1, off);
    s2 += __shfl_down(s2, off);
  }
  if (i == 0) {
    y0[n] = s0;
    y1[n] = s1;
    y2[n] = s2;
  }
}

// ---------------------------------------------------------------------------
// Launch
// ---------------------------------------------------------------------------
extern "C" void kernel_launch(void* const* d_in, const int* in_sizes, int n_in,
                              void* d_out, int out_size, void* d_ws,
                              size_t ws_size, hipStream_t stream) {
  const float* x = (const float*)d_in[0];
  const int* ei = (const int*)d_in[1];  // (2, E), int32
  const float* ew = (const float*)d_in[2];
  const float* W0 = (const float*)d_in[3];
  const float* W1 = (const float*)d_in[4];
  const float* W2 = (const float*)d_in[5];
  const float* a0 = (const float*)d_in[6];
  const float* a1 = (const float*)d_in[7];
  float* out = (float*)d_out;

  const int* row = ei;
  const int* col = ei + N_EDGES;

  // ws: dinv[N]f cnt[N]i bfill[256]i bkt[NB*BCAP]int2 ell[N*48]int2
  //     Wt0 Wt1 (192*64 bf16) xb F0 F1 (bf16) y0..z1 (f)
  const size_t need = (size_t)(2 * N_NODES + 256) * 4 +
                      (size_t)NB * BCAP * 8 + (size_t)N_NODES * ELL_S * 8 +
                      (size_t)(2 * 192 * DIM) * 2 +
                      (size_t)(3 * FEAT_TOTAL) * 2 + (size_t)(4 * N_NODES) * 4;
  if (ws_size < need) return;  // fail readable, not a fault
  float* dinv = (float*)d_ws;                // N floats
  int* cnt = (int*)(dinv + N_NODES);         // N ints
  int* bfill = cnt + N_NODES;                // 256 ints
  int2* bkt = (int2*)(bfill + 256);          // NB*BCAP
  int2* ell = bkt + (size_t)NB * BCAP;       // N*48
  uint16_t* Wt0 = (uint16_t*)(ell + (size_t)N_NODES * ELL_S);
  uint16_t* Wt1 = Wt0 + 192 * DIM;
  uint16_t* xb = Wt1 + 192 * DIM;
  uint16_t* F0 = xb + FEAT_TOTAL;
  uint16_t* F1 = F0 + FEAT_TOTAL;
  float* y0 = (float*)(F1 + FEAT_TOTAL);
  float* y1 = y0 + N_NODES;
  float* y2 = y1 + N_NODES;
  float* z1 = y2 + N_NODES;

  // Dropout keys: split(key(42), 2), partitionable
  uint32_t dk0_0, dk0_1, dk1_0, dk1_1;
  threefry2x32(0u, 42u, 0u, 0u, dk0_0, dk0_1);
  threefry2x32(0u, 42u, 0u, 1u, dk1_0, dk1_1);

  const int BLK = 256;
  const int gridN = (N_NODES + BLK - 1) / BLK;
  const int gridNF = (FEAT_TOTAL + BLK - 1) / BLK;    // wave per node
  const int gridNH = (N_NODES * 32 + BLK - 1) / BLK;  // half-wave per node
  const int gridT = (N_NODES + 63) / 64;              // 64-row gemm tiles

  // ---- build ELL (dinv fused into phaseC) + conversions ----
  hipMemsetAsync(bfill, 0, 256 * sizeof(int), stream);
  phaseA<<<NB, BLK, 0, stream>>>(row, col, ew, bfill, bkt, N_EDGES);
  phaseC<<<NB, BLK, 0, stream>>>(bfill, bkt, ell, cnt, dinv);
  normw_ell<<<gridNF, BLK, 0, stream>>>(ell, cnt, dinv, N_NODES);
  cvt_all<<<gridNF, BLK, 0, stream>>>(x, W0, W1, xb, Wt0, Wt1);

  // ---- layer 0: xb -> F0 (hop2 fused into gemm) ----
  prop_bf16<<<gridNH, BLK, 0, stream>>>(xb, F1, ell, cnt, N_NODES);
  gemm3_mfma_g<<<gridT, BLK, 0, stream>>>(xb, F1, ell, cnt, Wt0, F0, N_NODES,
                                          dk0_0, dk0_1, a0);
  // ---- layer 1: F0 -> F0 (in-place safe; gather source is F1) ----
  prop_bf16<<<gridNH, BLK, 0, stream>>>(F0, F1, ell, cnt, N_NODES);
  gemm3_mfma_g<<<gridT, BLK, 0, stream>>>(F0, F1, ell, cnt, Wt1, F0, N_NODES,
                                          dk1_0, dk1_1, a1);
  // ---- layer 2 (pushed-W): out = y0 + A(y1 + A y2), fp32 ----
  matvec3_bf16<<<gridNF, BLK, 0, stream>>>(F0, W2, y0, y1, y2, N_NODES);
  sprop_add_ell<<<gridN, BLK, 0, stream>>>(y2, y1, z1, ell, cnt, N_NODES);
  sprop_add_ell<<<gridN, BLK, 0, stream>>>(z1, y0, out, ell, cnt, N_NODES);
}

// Round 11
// 251.823 us; speedup vs baseline: 1.1973x; 1.1973x over previous
//
#include <hip/hip_runtime.h>
#include <stdint.h>

#define N_NODES 50000
#define N_EDGES 800000
#define DIM 64
#define FEAT_TOTAL (N_NODES * DIM)
#define ELL_S 48   // max degree bound; P(Poisson(16) >= 48) ~ 5e-11, guarded
#define NB 200     // coarse buckets (col / 250)
#define BROWS 250  // nodes per bucket
#define BCAP 6000  // bucket capacity; mean 4000, sd ~63 -> +31 sd, guarded
#define ECHUNK (N_EDGES / NB)  // 4000 edges per phaseA block
#define AST 200    // LDS row stride in bf16 (192 + 8 pad -> 2-way banks, free)

typedef __attribute__((ext_vector_type(8))) short bf16x8;
typedef __attribute__((ext_vector_type(4))) float f32x4;

// ---------------------------------------------------------------------------
// bf16 storage helpers (accumulate fp32, store bf16 RNE)
// ---------------------------------------------------------------------------
__device__ inline float bf2f(uint32_t h) { return __uint_as_float(h << 16); }
__device__ inline uint32_t f2bf(float f) {
  uint32_t u = __float_as_uint(f);
  return (u + 0x7fffu + ((u >> 16) & 1u)) >> 16;
}

// ---------------------------------------------------------------------------
// Threefry-2x32, 20 rounds — JAX-exact (validated R2: partitionable layout).
// ---------------------------------------------------------------------------
__host__ __device__ inline void threefry2x32(uint32_t k0, uint32_t k1,
                                             uint32_t x0, uint32_t x1,
                                             uint32_t& o0, uint32_t& o1) {
  uint32_t ks[3] = {k0, k1, k0 ^ k1 ^ 0x1BD11BDAu};
  x0 += ks[0];
  x1 += ks[1];
  const uint32_t R[2][4] = {{13u, 15u, 26u, 6u}, {17u, 29u, 16u, 24u}};
#pragma unroll
  for (int g = 0; g < 5; ++g) {
    const uint32_t* r = R[g & 1];
#pragma unroll
    for (int j = 0; j < 4; ++j) {
      x0 += x1;
      x1 = (x1 << r[j]) | (x1 >> (32u - r[j]));
      x1 ^= x0;
    }
    x0 += ks[(g + 1) % 3];
    x1 += ks[(g + 2) % 3] + (uint32_t)(g + 1);
  }
  o0 = x0;
  o1 = x1;
}

// ===========================================================================
// Phase A: coarse-bucket edges by col/BROWS. LDS histogram -> one global
// atomic per (block,bucket); contiguous run writes into fixed-cap buckets.
// entry = { row | col_local<<17 , w } (row<2^17, col_local<2^8).
// ===========================================================================
__global__ __launch_bounds__(256) void phaseA(
    const int* __restrict__ row, const int* __restrict__ col,
    const float* __restrict__ w, int* __restrict__ bfill,
    int2* __restrict__ bkt, int E) {
  __shared__ int hist[NB], base[NB], off[NB];
  int t = threadIdx.x;
  int lo = blockIdx.x * ECHUNK;
  int hi = min(lo + ECHUNK, E);
  for (int i = t; i < NB; i += 256) hist[i] = 0;
  __syncthreads();
  for (int e = lo + t; e < hi; e += 256) atomicAdd(&hist[col[e] / BROWS], 1);
  __syncthreads();
  for (int i = t; i < NB; i += 256) {
    base[i] = atomicAdd(&bfill[i], hist[i]);
    off[i] = 0;
  }
  __syncthreads();
  for (int e = lo + t; e < hi; e += 256) {
    int c = col[e];
    int bin = c / BROWS;
    int rank = atomicAdd(&off[bin], 1);
    int dest = base[bin] + rank;
    if (dest < BCAP) {
      int2 ent;
      ent.x = row[e] | ((c - bin * BROWS) << 17);
      ent.y = __float_as_int(w[e]);
      bkt[(size_t)bin * BCAP + dest] = ent;
    }
  }
}

// ===========================================================================
// Phase C: one block per bucket; ELL rows L2-resident -> stores combine.
// LDS atomics assign slots + accumulate deg; dinv computed in-block (bucket
// owns ALL edges into its 250 nodes, so deg is complete here).
// ===========================================================================
__global__ __launch_bounds__(256) void phaseC(
    const int* __restrict__ bfill, const int2* __restrict__ bkt,
    int2* __restrict__ ell, int* __restrict__ cnt, float* __restrict__ dinv) {
  __shared__ int lcnt[BROWS];
  __shared__ float ldeg[BROWS];
  int t = threadIdx.x;
  int b = blockIdx.x;
  for (int i = t; i < BROWS; i += 256) {
    lcnt[i] = 0;
    ldeg[i] = 0.0f;
  }
  __syncthreads();
  int sz = min(bfill[b], BCAP);
  const int2* src = bkt + (size_t)b * BCAP;
  for (int i = t; i < sz; i += 256) {
    int2 ent = src[i];
    int cl = (ent.x >> 17) & 0xff;
    int r = ent.x & 0x1ffff;
    float wv = __int_as_float(ent.y);
    int slot = atomicAdd(&lcnt[cl], 1);
    if (slot < ELL_S) {
      int2 o;
      o.x = r;
      o.y = ent.y;
      ell[(size_t)(b * BROWS + cl) * ELL_S + slot] = o;
    }
    atomicAdd(&ldeg[cl], wv);
  }
  __syncthreads();
  for (int i = t; i < BROWS; i += 256) {
    cnt[b * BROWS + i] = lcnt[i];
    float d = ldeg[i];
    dinv[b * BROWS + i] = (d > 0.0f) ? rsqrtf(fmaxf(d, 1e-12f)) : 0.0f;
  }
}

// wave per node, lane per slot: weight <- dinv[src]*w*dinv[dst]
__global__ void normw_ell(int2* __restrict__ ell, const int* __restrict__ cnt,
                          const float* __restrict__ dinv, int n_nodes) {
  int gid = blockIdx.x * blockDim.x + threadIdx.x;
  int n = gid >> 6;
  if (n >= n_nodes) return;
  int lane = threadIdx.x & 63;
  int c = min(cnt[n], ELL_S);
  if (lane >= c) return;
  float dn = dinv[n];
  int2 ent = ell[(size_t)n * ELL_S + lane];
  ent.y = __float_as_int(dinv[ent.x] * __int_as_float(ent.y) * dn);
  ell[(size_t)n * ELL_S + lane] = ent;
}

// Conversions: x -> bf16 xb; W0/W1 (fp32 [192][64] k-major) -> bf16 [64][192]
__global__ void cvt_all(const float* __restrict__ x,
                        const float* __restrict__ W0,
                        const float* __restrict__ W1,
                        uint16_t* __restrict__ xb, uint16_t* __restrict__ Wt0,
                        uint16_t* __restrict__ Wt1) {
  int id = blockIdx.x * blockDim.x + threadIdx.x;
  if (id < FEAT_TOTAL) xb[id] = (uint16_t)f2bf(x[id]);
  if (id < 192 * DIM) {
    int kk = id >> 6;
    int j = id & 63;
    Wt0[j * 192 + kk] = (uint16_t)f2bf(W0[id]);
    Wt1[j * 192 + kk] = (uint16_t)f2bf(W1[id]);
  }
}

// ===========================================================================
// Propagate bf16: TWO nodes per wave (32 lanes each); per half:
// eg 0..3, fc 0..7 (uint4 = 8 bf16); unroll2 -> 8 chains/node, 16/wave.
// ===========================================================================
__global__ void prop_bf16(const uint16_t* __restrict__ src,
                          uint16_t* __restrict__ dst,
                          const int2* __restrict__ ell,
                          const int* __restrict__ cnt, int n_nodes) {
  int gid = blockIdx.x * blockDim.x + threadIdx.x;
  int n = gid >> 5;  // node per 32-lane half
  if (n >= n_nodes) return;
  int hl = threadIdx.x & 31;
  int eg = hl >> 3;  // 0..3
  int fc = hl & 7;   // 0..7, 8 bf16 each
  int c = min(cnt[n], ELL_S);
  const int2* p = ell + (size_t)n * ELL_S;
  float acc[8] = {0.f, 0.f, 0.f, 0.f, 0.f, 0.f, 0.f, 0.f};
  int k = eg;
  for (; k + 4 < c; k += 8) {
    int2 e0 = p[k];
    int2 e1 = p[k + 4];
    float w0 = __int_as_float(e0.y);
    float w1 = __int_as_float(e1.y);
    uint4 v0 = *(const uint4*)&src[e0.x * DIM + fc * 8];
    uint4 v1 = *(const uint4*)&src[e1.x * DIM + fc * 8];
    acc[0] += bf2f(v0.x & 0xffffu) * w0 + bf2f(v1.x & 0xffffu) * w1;
    acc[1] += bf2f(v0.x >> 16) * w0 + bf2f(v1.x >> 16) * w1;
    acc[2] += bf2f(v0.y & 0xffffu) * w0 + bf2f(v1.y & 0xffffu) * w1;
    acc[3] += bf2f(v0.y >> 16) * w0 + bf2f(v1.y >> 16) * w1;
    acc[4] += bf2f(v0.z & 0xffffu) * w0 + bf2f(v1.z & 0xffffu) * w1;
    acc[5] += bf2f(v0.z >> 16) * w0 + bf2f(v1.z >> 16) * w1;
    acc[6] += bf2f(v0.w & 0xffffu) * w0 + bf2f(v1.w & 0xffffu) * w1;
    acc[7] += bf2f(v0.w >> 16) * w0 + bf2f(v1.w >> 16) * w1;
  }
  if (k < c) {
    int2 e0 = p[k];
    float w0 = __int_as_float(e0.y);
    uint4 v0 = *(const uint4*)&src[e0.x * DIM + fc * 8];
    acc[0] += bf2f(v0.x & 0xffffu) * w0;
    acc[1] += bf2f(v0.x >> 16) * w0;
    acc[2] += bf2f(v0.y & 0xffffu) * w0;
    acc[3] += bf2f(v0.y >> 16) * w0;
    acc[4] += bf2f(v0.z & 0xffffu) * w0;
    acc[5] += bf2f(v0.z >> 16) * w0;
    acc[6] += bf2f(v0.w & 0xffffu) * w0;
    acc[7] += bf2f(v0.w >> 16) * w0;
  }
#pragma unroll
  for (int m = 8; m <= 16; m <<= 1) {
#pragma unroll
    for (int j = 0; j < 8; ++j) acc[j] += __shfl_xor(acc[j], m);
  }
  if (eg == 0) {
    uint4 r;
    r.x = f2bf(acc[0]) | (f2bf(acc[1]) << 16);
    r.y = f2bf(acc[2]) | (f2bf(acc[3]) << 16);
    r.z = f2bf(acc[4]) | (f2bf(acc[5]) << 16);
    r.w = f2bf(acc[6]) | (f2bf(acc[7]) << 16);
    *(uint4*)&dst[(size_t)n * DIM + fc * 8] = r;
  }
}

__global__ void sprop_add_ell(const float* __restrict__ src,
                              const float* __restrict__ addv,
                              float* __restrict__ dst,
                              const int2* __restrict__ ell,
                              const int* __restrict__ cnt, int n_nodes) {
  int n = blockIdx.x * blockDim.x + threadIdx.x;
  if (n >= n_nodes) return;
  int c = min(cnt[n], ELL_S);
  const int2* p = ell + (size_t)n * ELL_S;
  float acc = addv[n];
  for (int k = 0; k < c; ++k)
    acc += __int_as_float(p[k].y) * src[p[k].x];
  dst[n] = acc;
}

// ===========================================================================
// gemm3 via MFMA 16x16x32 bf16. Block = 64 dst rows x 64 cols, 4 waves.
// sA = [X|P1|P2] rows (bf16, AST-padded, 25.6 KB — 6 blocks/CU).
// B-fragments loaded straight from global Wt into registers (Wt = 24.6 KB,
// identical for every block -> L1-resident; saves sB LDS + 1536 LDS stores).
// Layouts (m89/m120 verified): A[m=lane&15][k=quad*8+j]; B[n=lane&15][k];
// C/D col=lane&15, row=quad*4+reg. Epilogue: threefry dropout + PReLU.
// In-place safe (out==X): block stages its own rows before writing them.
// ===========================================================================
__global__ __launch_bounds__(256) void gemm3_mfma(
    const uint16_t* X, const uint16_t* __restrict__ P1,
    const uint16_t* __restrict__ P2, const uint16_t* __restrict__ Wt,
    uint16_t* out, int n_nodes, uint32_t k0, uint32_t k1,
    const float* __restrict__ a) {
  __shared__ uint16_t sA[64 * AST];  // 25600 B
  int t = threadIdx.x;
  int n0 = blockIdx.x * 64;
  int wv = t >> 6;
  int lane = t & 63;
  int lm = lane & 15;
  int quad = lane >> 4;
  // ---- B-fragments from global (issued early; independent of staging) ----
  bf16x8 bfrag[6];
  {
    const uint16_t* pB = &Wt[(wv * 16 + lm) * 192 + quad * 8];
#pragma unroll
    for (int ks = 0; ks < 6; ++ks) bfrag[ks] = *(const bf16x8*)(pB + ks * 32);
  }
  // ---- stage A: X (cols 0..63), P1 (64..127), P2 (128..191) ----
#pragma unroll
  for (int m = 0; m < 3; ++m) {
    const uint16_t* S = (m == 0) ? X : ((m == 1) ? P1 : P2);
#pragma unroll
    for (int it = 0; it < 2; ++it) {
      int chunk = t + it * 256;  // 64 rows x 8 uint4-chunks
      int rrow = chunk >> 3;
      int cc = chunk & 7;
      int nc = min(n0 + rrow, n_nodes - 1);
      uint4 v = *(const uint4*)&S[(size_t)nc * DIM + cc * 8];
      *(uint4*)&sA[rrow * AST + m * DIM + cc * 8] = v;
    }
  }
  __syncthreads();
  f32x4 acc[4] = {};  // row-tiles 0..3
  const uint16_t* pA = &sA[lm * AST + quad * 8];
#pragma unroll
  for (int ks = 0; ks < 6; ++ks) {
#pragma unroll
    for (int rt = 0; rt < 4; ++rt) {
      bf16x8 af = *(const bf16x8*)(pA + rt * 16 * AST + ks * 32);
      acc[rt] =
          __builtin_amdgcn_mfma_f32_16x16x32_bf16(af, bfrag[ks], acc[rt], 0, 0, 0);
    }
  }
  // ---- epilogue: dropout (JAX threefry) + PReLU, bf16 store ----
  float al = a[0];
  int col = wv * 16 + lm;
#pragma unroll
  for (int rt = 0; rt < 4; ++rt) {
#pragma unroll
    for (int r = 0; r < 4; ++r) {
      int n = n0 + rt * 16 + quad * 4 + r;
      if (n < n_nodes) {
        float v = acc[rt][r];
        uint32_t idx = (uint32_t)(n * DIM + col);
        uint32_t o0, o1;
        threefry2x32(k0, k1, 0u, idx, o0, o1);
        v = ((o0 ^ o1) & 0x80000000u) ? 0.0f : (v + v);  // dropout p=0.5
        v = (v >= 0.0f) ? v : al * v;                     // PReLU
        out[(size_t)n * DIM + col] = (uint16_t)f2bf(v);
      }
    }
  }
}

// Layer-2 matvecs from bf16 F: y_k[n] = sum_i F[n][i]*W2[k][i][0]
__global__ void matvec3_bf16(const uint16_t* __restrict__ F,
                             const float* __restrict__ W2,
                             float* __restrict__ y0, float* __restrict__ y1,
                             float* __restrict__ y2, int n_nodes) {
  int gid = blockIdx.x * blockDim.x + threadIdx.x;
  int n = gid >> 6;
  int i = gid & 63;
  if (n >= n_nodes) return;
  float v = bf2f((uint32_t)F[(size_t)n * DIM + i]);
  float s0 = v * W2[i], s1 = v * W2[DIM + i], s2 = v * W2[2 * DIM + i];
#pragma unroll
  for (int off = 32; off > 0; off >>= 1) {
    s0 += __shfl_down(s0, off);
    s1 += __shfl_down(s1, off);
    s2 += __shfl_down(s2, off);
  }
  if (i == 0) {
    y0[n] = s0;
    y1[n] = s1;
    y2[n] = s2;
  }
}

// ---------------------------------------------------------------------------
// Launch
// ---------------------------------------------------------------------------
extern "C" void kernel_launch(void* const* d_in, const int* in_sizes, int n_in,
                              void* d_out, int out_size, void* d_ws,
                              size_t ws_size, hipStream_t stream) {
  const float* x = (const float*)d_in[0];
  const int* ei = (const int*)d_in[1];  // (2, E), int32
  const float* ew = (const float*)d_in[2];
  const float* W0 = (const float*)d_in[3];
  const float* W1 = (const float*)d_in[4];
  const float* W2 = (const float*)d_in[5];
  const float* a0 = (const float*)d_in[6];
  const float* a1 = (const float*)d_in[7];
  float* out = (float*)d_out;

  const int* row = ei;
  const int* col = ei + N_EDGES;

  // ws: dinv[N]f cnt[N]i bfill[256]i bkt[NB*BCAP]int2 ell[N*48]int2
  //     Wt0 Wt1 (192*64 bf16) xb F0 F1 F2 (bf16) y0..z1 (f)
  const size_t need = (size_t)(2 * N_NODES + 256) * 4 +
                      (size_t)NB * BCAP * 8 + (size_t)N_NODES * ELL_S * 8 +
                      (size_t)(2 * 192 * DIM) * 2 +
                      (size_t)(4 * FEAT_TOTAL) * 2 + (size_t)(4 * N_NODES) * 4;
  if (ws_size < need) return;  // fail readable, not a fault
  float* dinv = (float*)d_ws;                // N floats
  int* cnt = (int*)(dinv + N_NODES);         // N ints
  int* bfill = cnt + N_NODES;                // 256 ints
  int2* bkt = (int2*)(bfill + 256);          // NB*BCAP
  int2* ell = bkt + (size_t)NB * BCAP;       // N*48
  uint16_t* Wt0 = (uint16_t*)(ell + (size_t)N_NODES * ELL_S);
  uint16_t* Wt1 = Wt0 + 192 * DIM;
  uint16_t* xb = Wt1 + 192 * DIM;
  uint16_t* F0 = xb + FEAT_TOTAL;
  uint16_t* F1 = F0 + FEAT_TOTAL;
  uint16_t* F2 = F1 + FEAT_TOTAL;
  float* y0 = (float*)(F2 + FEAT_TOTAL);
  float* y1 = y0 + N_NODES;
  float* y2 = y1 + N_NODES;
  float* z1 = y2 + N_NODES;

  // Dropout keys: split(key(42), 2), partitionable
  uint32_t dk0_0, dk0_1, dk1_0, dk1_1;
  threefry2x32(0u, 42u, 0u, 0u, dk0_0, dk0_1);
  threefry2x32(0u, 42u, 0u, 1u, dk1_0, dk1_1);

  const int BLK = 256;
  const int gridN = (N_NODES + BLK - 1) / BLK;
  const int gridNF = (FEAT_TOTAL + BLK - 1) / BLK;    // wave per node
  const int gridNH = (N_NODES * 32 + BLK - 1) / BLK;  // half-wave per node
  const int gridT = (N_NODES + 63) / 64;              // 64-row gemm tiles

  // ---- build ELL (dinv fused into phaseC) + conversions ----
  hipMemsetAsync(bfill, 0, 256 * sizeof(int), stream);
  phaseA<<<NB, BLK, 0, stream>>>(row, col, ew, bfill, bkt, N_EDGES);
  phaseC<<<NB, BLK, 0, stream>>>(bfill, bkt, ell, cnt, dinv);
  normw_ell<<<gridNF, BLK, 0, stream>>>(ell, cnt, dinv, N_NODES);
  cvt_all<<<gridNF, BLK, 0, stream>>>(x, W0, W1, xb, Wt0, Wt1);

  // ---- layer 0: xb -> F0 ----
  prop_bf16<<<gridNH, BLK, 0, stream>>>(xb, F1, ell, cnt, N_NODES);
  prop_bf16<<<gridNH, BLK, 0, stream>>>(F1, F2, ell, cnt, N_NODES);
  gemm3_mfma<<<gridT, BLK, 0, stream>>>(xb, F1, F2, Wt0, F0, N_NODES, dk0_0,
                                        dk0_1, a0);
  // ---- layer 1: F0 -> F0 (in-place safe) ----
  prop_bf16<<<gridNH, BLK, 0, stream>>>(F0, F1, ell, cnt, N_NODES);
  prop_bf16<<<gridNH, BLK, 0, stream>>>(F1, F2, ell, cnt, N_NODES);
  gemm3_mfma<<<gridT, BLK, 0, stream>>>(F0, F1, F2, Wt1, F0, N_NODES, dk1_0,
                                        dk1_1, a1);
  // ---- layer 2 (pushed-W): out = y0 + A(y1 + A y2), fp32 ----
  matvec3_bf16<<<gridNF, BLK, 0, stream>>>(F0, W2, y0, y1, y2, N_NODES);
  sprop_add_ell<<<gridN, BLK, 0, stream>>>(y2, y1, z1, ell, cnt, N_NODES);
  sprop_add_ell<<<gridN, BLK, 0, stream>>>(z1, y0, out, ell, cnt, N_NODES);
}

// Round 12
// 247.820 us; speedup vs baseline: 1.2166x; 1.0162x over previous
//
#include <hip/hip_runtime.h>
#include <stdint.h>

#define N_NODES 50000
#define N_EDGES 800000
#define DIM 64
#define FEAT_TOTAL (N_NODES * DIM)
#define ELL_S 48   // max degree bound; P(Poisson(16) >= 48) ~ 5e-11, guarded
#define NB 200     // coarse buckets (col / 250)
#define BROWS 250  // nodes per bucket
#define BCAP 6000  // bucket capacity; mean 4000, sd ~63 -> +31 sd, guarded
#define ECHUNK (N_EDGES / NB)  // 4000 edges per phaseA block
#define AST 200    // LDS row stride in bf16 (192 + 8 pad -> 2-way banks, free)

typedef __attribute__((ext_vector_type(8))) short bf16x8;
typedef __attribute__((ext_vector_type(4))) float f32x4;

// ---------------------------------------------------------------------------
// bf16 storage helpers (accumulate fp32, store bf16 RNE)
// ---------------------------------------------------------------------------
__device__ inline float bf2f(uint32_t h) { return __uint_as_float(h << 16); }
__device__ inline uint32_t f2bf(float f) {
  uint32_t u = __float_as_uint(f);
  return (u + 0x7fffu + ((u >> 16) & 1u)) >> 16;
}

// ---------------------------------------------------------------------------
// Threefry-2x32, 20 rounds — JAX-exact (validated R2: partitionable layout).
// ---------------------------------------------------------------------------
__host__ __device__ inline void threefry2x32(uint32_t k0, uint32_t k1,
                                             uint32_t x0, uint32_t x1,
                                             uint32_t& o0, uint32_t& o1) {
  uint32_t ks[3] = {k0, k1, k0 ^ k1 ^ 0x1BD11BDAu};
  x0 += ks[0];
  x1 += ks[1];
  const uint32_t R[2][4] = {{13u, 15u, 26u, 6u}, {17u, 29u, 16u, 24u}};
#pragma unroll
  for (int g = 0; g < 5; ++g) {
    const uint32_t* r = R[g & 1];
#pragma unroll
    for (int j = 0; j < 4; ++j) {
      x0 += x1;
      x1 = (x1 << r[j]) | (x1 >> (32u - r[j]));
      x1 ^= x0;
    }
    x0 += ks[(g + 1) % 3];
    x1 += ks[(g + 2) % 3] + (uint32_t)(g + 1);
  }
  o0 = x0;
  o1 = x1;
}

// ===========================================================================
// Phase A: coarse-bucket edges by col/BROWS. LDS histogram -> one global
// atomic per (block,bucket); contiguous run writes into fixed-cap buckets.
// entry = { row | col_local<<17 , w } (row<2^17, col_local<2^8).
// ===========================================================================
__global__ __launch_bounds__(256) void phaseA(
    const int* __restrict__ row, const int* __restrict__ col,
    const float* __restrict__ w, int* __restrict__ bfill,
    int2* __restrict__ bkt, int E) {
  __shared__ int hist[NB], base[NB], off[NB];
  int t = threadIdx.x;
  int lo = blockIdx.x * ECHUNK;
  int hi = min(lo + ECHUNK, E);
  for (int i = t; i < NB; i += 256) hist[i] = 0;
  __syncthreads();
  for (int e = lo + t; e < hi; e += 256) atomicAdd(&hist[col[e] / BROWS], 1);
  __syncthreads();
  for (int i = t; i < NB; i += 256) {
    base[i] = atomicAdd(&bfill[i], hist[i]);
    off[i] = 0;
  }
  __syncthreads();
  for (int e = lo + t; e < hi; e += 256) {
    int c = col[e];
    int bin = c / BROWS;
    int rank = atomicAdd(&off[bin], 1);
    int dest = base[bin] + rank;
    if (dest < BCAP) {
      int2 ent;
      ent.x = row[e] | ((c - bin * BROWS) << 17);
      ent.y = __float_as_int(w[e]);
      bkt[(size_t)bin * BCAP + dest] = ent;
    }
  }
}

// ===========================================================================
// Phase C: one block per bucket; ELL rows L2-resident -> stores combine.
// LDS atomics assign slots + accumulate deg; dinv computed in-block (bucket
// owns ALL edges into its 250 nodes, so deg is complete here).
// ===========================================================================
__global__ __launch_bounds__(256) void phaseC(
    const int* __restrict__ bfill, const int2* __restrict__ bkt,
    int2* __restrict__ ell, int* __restrict__ cnt, float* __restrict__ dinv) {
  __shared__ int lcnt[BROWS];
  __shared__ float ldeg[BROWS];
  int t = threadIdx.x;
  int b = blockIdx.x;
  for (int i = t; i < BROWS; i += 256) {
    lcnt[i] = 0;
    ldeg[i] = 0.0f;
  }
  __syncthreads();
  int sz = min(bfill[b], BCAP);
  const int2* src = bkt + (size_t)b * BCAP;
  for (int i = t; i < sz; i += 256) {
    int2 ent = src[i];
    int cl = (ent.x >> 17) & 0xff;
    int r = ent.x & 0x1ffff;
    float wv = __int_as_float(ent.y);
    int slot = atomicAdd(&lcnt[cl], 1);
    if (slot < ELL_S) {
      int2 o;
      o.x = r;
      o.y = ent.y;
      ell[(size_t)(b * BROWS + cl) * ELL_S + slot] = o;
    }
    atomicAdd(&ldeg[cl], wv);
  }
  __syncthreads();
  for (int i = t; i < BROWS; i += 256) {
    cnt[b * BROWS + i] = lcnt[i];
    float d = ldeg[i];
    dinv[b * BROWS + i] = (d > 0.0f) ? rsqrtf(fmaxf(d, 1e-12f)) : 0.0f;
  }
}

// ===========================================================================
// Fused: (a) normw — wave per node, lane per slot: w <- dinv[src]*w*dinv[dst]
//        (b) x -> bf16 xb   (c) W0/W1 fp32 [192][64] -> bf16 Wt [64][192]
// All independent; one launch over gridNF.
// ===========================================================================
__global__ void normw_cvt(int2* __restrict__ ell, const int* __restrict__ cnt,
                          const float* __restrict__ dinv,
                          const float* __restrict__ x,
                          const float* __restrict__ W0,
                          const float* __restrict__ W1,
                          uint16_t* __restrict__ xb, uint16_t* __restrict__ Wt0,
                          uint16_t* __restrict__ Wt1, int n_nodes) {
  int gid = blockIdx.x * blockDim.x + threadIdx.x;
  // (a) normw
  int n = gid >> 6;
  if (n < n_nodes) {
    int lane = threadIdx.x & 63;
    int c = min(cnt[n], ELL_S);
    if (lane < c) {
      float dn = dinv[n];
      int2 ent = ell[(size_t)n * ELL_S + lane];
      ent.y = __float_as_int(dinv[ent.x] * __int_as_float(ent.y) * dn);
      ell[(size_t)n * ELL_S + lane] = ent;
    }
  }
  // (b) x -> bf16
  if (gid < FEAT_TOTAL) xb[gid] = (uint16_t)f2bf(x[gid]);
  // (c) weights transpose+convert
  if (gid < 192 * DIM) {
    int kk = gid >> 6;
    int j = gid & 63;
    Wt0[j * 192 + kk] = (uint16_t)f2bf(W0[gid]);
    Wt1[j * 192 + kk] = (uint16_t)f2bf(W1[gid]);
  }
}

// ===========================================================================
// Propagate bf16: TWO nodes per wave (32 lanes each); per half:
// eg 0..3, fc 0..7 (uint4 = 8 bf16). MLP-restructured: all 4 chain entries
// preloaded unconditionally (ELL rows always have 48 allocated slots, so
// p[eg+12] <= p[15] is safe memory) -> 4 entry loads + up to 4 gathers all
// in flight, no dependent entry->gather rounds for c<=16 (common case).
// ===========================================================================
__global__ void prop_bf16(const uint16_t* __restrict__ src,
                          uint16_t* __restrict__ dst,
                          const int2* __restrict__ ell,
                          const int* __restrict__ cnt, int n_nodes) {
  int gid = blockIdx.x * blockDim.x + threadIdx.x;
  int n = gid >> 5;  // node per 32-lane half
  if (n >= n_nodes) return;
  int hl = threadIdx.x & 31;
  int eg = hl >> 3;  // 0..3
  int fc = hl & 7;   // 0..7, 8 bf16 each
  int c = min(cnt[n], ELL_S);
  const int2* p = ell + (size_t)n * ELL_S;
  // Preload 4 entries per chain (unconditional; slots 0..15 always allocated)
  int2 e[4];
#pragma unroll
  for (int i = 0; i < 4; ++i) e[i] = p[eg + 4 * i];
  float acc[8] = {0.f, 0.f, 0.f, 0.f, 0.f, 0.f, 0.f, 0.f};
#pragma unroll
  for (int i = 0; i < 4; ++i) {
    int k = eg + 4 * i;
    if (k < c) {
      float w0 = __int_as_float(e[i].y);
      uint4 v0 = *(const uint4*)&src[e[i].x * DIM + fc * 8];
      acc[0] += bf2f(v0.x & 0xffffu) * w0;
      acc[1] += bf2f(v0.x >> 16) * w0;
      acc[2] += bf2f(v0.y & 0xffffu) * w0;
      acc[3] += bf2f(v0.y >> 16) * w0;
      acc[4] += bf2f(v0.z & 0xffffu) * w0;
      acc[5] += bf2f(v0.z >> 16) * w0;
      acc[6] += bf2f(v0.w & 0xffffu) * w0;
      acc[7] += bf2f(v0.w >> 16) * w0;
    }
  }
  // Rare tail (c > 16)
  for (int k = 16 + eg; k < c; k += 4) {
    int2 ee = p[k];
    float w0 = __int_as_float(ee.y);
    uint4 v0 = *(const uint4*)&src[ee.x * DIM + fc * 8];
    acc[0] += bf2f(v0.x & 0xffffu) * w0;
    acc[1] += bf2f(v0.x >> 16) * w0;
    acc[2] += bf2f(v0.y & 0xffffu) * w0;
    acc[3] += bf2f(v0.y >> 16) * w0;
    acc[4] += bf2f(v0.z & 0xffffu) * w0;
    acc[5] += bf2f(v0.z >> 16) * w0;
    acc[6] += bf2f(v0.w & 0xffffu) * w0;
    acc[7] += bf2f(v0.w >> 16) * w0;
  }
#pragma unroll
  for (int m = 8; m <= 16; m <<= 1) {
#pragma unroll
    for (int j = 0; j < 8; ++j) acc[j] += __shfl_xor(acc[j], m);
  }
  if (eg == 0) {
    uint4 r;
    r.x = f2bf(acc[0]) | (f2bf(acc[1]) << 16);
    r.y = f2bf(acc[2]) | (f2bf(acc[3]) << 16);
    r.z = f2bf(acc[4]) | (f2bf(acc[5]) << 16);
    r.w = f2bf(acc[6]) | (f2bf(acc[7]) << 16);
    *(uint4*)&dst[(size_t)n * DIM + fc * 8] = r;
  }
}

__global__ void sprop_add_ell(const float* __restrict__ src,
                              const float* __restrict__ addv,
                              float* __restrict__ dst,
                              const int2* __restrict__ ell,
                              const int* __restrict__ cnt, int n_nodes) {
  int n = blockIdx.x * blockDim.x + threadIdx.x;
  if (n >= n_nodes) return;
  int c = min(cnt[n], ELL_S);
  const int2* p = ell + (size_t)n * ELL_S;
  float acc = addv[n];
  for (int k = 0; k < c; ++k)
    acc += __int_as_float(p[k].y) * src[p[k].x];
  dst[n] = acc;
}

// ===========================================================================
// gemm3 via MFMA 16x16x32 bf16. Block = 64 dst rows x 64 cols, 4 waves.
// sA = [X|P1|P2] rows (bf16, AST-padded, 25.6 KB — 6 blocks/CU).
// B-fragments loaded straight from global Wt into registers (L1-resident).
// Layouts (m89/m120 verified): A[m=lane&15][k=quad*8+j]; B[n=lane&15][k];
// C/D col=lane&15, row=quad*4+reg. Epilogue: threefry dropout + PReLU.
// In-place safe (out==X): block stages its own rows before writing them.
// ===========================================================================
__global__ __launch_bounds__(256) void gemm3_mfma(
    const uint16_t* X, const uint16_t* __restrict__ P1,
    const uint16_t* __restrict__ P2, const uint16_t* __restrict__ Wt,
    uint16_t* out, int n_nodes, uint32_t k0, uint32_t k1,
    const float* __restrict__ a) {
  __shared__ uint16_t sA[64 * AST];  // 25600 B
  int t = threadIdx.x;
  int n0 = blockIdx.x * 64;
  int wv = t >> 6;
  int lane = t & 63;
  int lm = lane & 15;
  int quad = lane >> 4;
  // ---- B-fragments from global (issued early; independent of staging) ----
  bf16x8 bfrag[6];
  {
    const uint16_t* pB = &Wt[(wv * 16 + lm) * 192 + quad * 8];
#pragma unroll
    for (int ks = 0; ks < 6; ++ks) bfrag[ks] = *(const bf16x8*)(pB + ks * 32);
  }
  // ---- stage A: X (cols 0..63), P1 (64..127), P2 (128..191) ----
#pragma unroll
  for (int m = 0; m < 3; ++m) {
    const uint16_t* S = (m == 0) ? X : ((m == 1) ? P1 : P2);
#pragma unroll
    for (int it = 0; it < 2; ++it) {
      int chunk = t + it * 256;  // 64 rows x 8 uint4-chunks
      int rrow = chunk >> 3;
      int cc = chunk & 7;
      int nc = min(n0 + rrow, n_nodes - 1);
      uint4 v = *(const uint4*)&S[(size_t)nc * DIM + cc * 8];
      *(uint4*)&sA[rrow * AST + m * DIM + cc * 8] = v;
    }
  }
  __syncthreads();
  f32x4 acc[4] = {};  // row-tiles 0..3
  const uint16_t* pA = &sA[lm * AST + quad * 8];
#pragma unroll
  for (int ks = 0; ks < 6; ++ks) {
#pragma unroll
    for (int rt = 0; rt < 4; ++rt) {
      bf16x8 af = *(const bf16x8*)(pA + rt * 16 * AST + ks * 32);
      acc[rt] =
          __builtin_amdgcn_mfma_f32_16x16x32_bf16(af, bfrag[ks], acc[rt], 0, 0, 0);
    }
  }
  // ---- epilogue: dropout (JAX threefry) + PReLU, bf16 store ----
  float al = a[0];
  int col = wv * 16 + lm;
#pragma unroll
  for (int rt = 0; rt < 4; ++rt) {
#pragma unroll
    for (int r = 0; r < 4; ++r) {
      int n = n0 + rt * 16 + quad * 4 + r;
      if (n < n_nodes) {
        float v = acc[rt][r];
        uint32_t idx = (uint32_t)(n * DIM + col);
        uint32_t o0, o1;
        threefry2x32(k0, k1, 0u, idx, o0, o1);
        v = ((o0 ^ o1) & 0x80000000u) ? 0.0f : (v + v);  // dropout p=0.5
        v = (v >= 0.0f) ? v : al * v;                     // PReLU
        out[(size_t)n * DIM + col] = (uint16_t)f2bf(v);
      }
    }
  }
}

// Layer-2 matvecs from bf16 F: y_k[n] = sum_i F[n][i]*W2[k][i][0]
__global__ void matvec3_bf16(const uint16_t* __restrict__ F,
                             const float* __restrict__ W2,
                             float* __restrict__ y0, float* __restrict__ y1,
                             float* __restrict__ y2, int n_nodes) {
  int gid = blockIdx.x * blockDim.x + threadIdx.x;
  int n = gid >> 6;
  int i = gid & 63;
  if (n >= n_nodes) return;
  float v = bf2f((uint32_t)F[(size_t)n * DIM + i]);
  float s0 = v * W2[i], s1 = v * W2[DIM + i], s2 = v * W2[2 * DIM + i];
#pragma unroll
  for (int off = 32; off > 0; off >>= 1) {
    s0 += __shfl_down(s0, off);
    s1 += __shfl_down(s1, off);
    s2 += __shfl_down(s2, off);
  }
  if (i == 0) {
    y0[n] = s0;
    y1[n] = s1;
    y2[n] = s2;
  }
}

// ---------------------------------------------------------------------------
// Launch
// ---------------------------------------------------------------------------
extern "C" void kernel_launch(void* const* d_in, const int* in_sizes, int n_in,
                              void* d_out, int out_size, void* d_ws,
                              size_t ws_size, hipStream_t stream) {
  const float* x = (const float*)d_in[0];
  const int* ei = (const int*)d_in[1];  // (2, E), int32
  const float* ew = (const float*)d_in[2];
  const float* W0 = (const float*)d_in[3];
  const float* W1 = (const float*)d_in[4];
  const float* W2 = (const float*)d_in[5];
  const float* a0 = (const float*)d_in[6];
  const float* a1 = (const float*)d_in[7];
  float* out = (float*)d_out;

  const int* row = ei;
  const int* col = ei + N_EDGES;

  // ws: dinv[N]f cnt[N]i bfill[256]i bkt[NB*BCAP]int2 ell[N*48]int2
  //     Wt0 Wt1 (192*64 bf16) xb F0 F1 F2 (bf16) y0..z1 (f)
  const size_t need = (size_t)(2 * N_NODES + 256) * 4 +
                      (size_t)NB * BCAP * 8 + (size_t)N_NODES * ELL_S * 8 +
                      (size_t)(2 * 192 * DIM) * 2 +
                      (size_t)(4 * FEAT_TOTAL) * 2 + (size_t)(4 * N_NODES) * 4;
  if (ws_size < need) return;  // fail readable, not a fault
  float* dinv = (float*)d_ws;                // N floats
  int* cnt = (int*)(dinv + N_NODES);         // N ints
  int* bfill = cnt + N_NODES;                // 256 ints
  int2* bkt = (int2*)(bfill + 256);          // NB*BCAP
  int2* ell = bkt + (size_t)NB * BCAP;       // N*48
  uint16_t* Wt0 = (uint16_t*)(ell + (size_t)N_NODES * ELL_S);
  uint16_t* Wt1 = Wt0 + 192 * DIM;
  uint16_t* xb = Wt1 + 192 * DIM;
  uint16_t* F0 = xb + FEAT_TOTAL;
  uint16_t* F1 = F0 + FEAT_TOTAL;
  uint16_t* F2 = F1 + FEAT_TOTAL;
  float* y0 = (float*)(F2 + FEAT_TOTAL);
  float* y1 = y0 + N_NODES;
  float* y2 = y1 + N_NODES;
  float* z1 = y2 + N_NODES;

  // Dropout keys: split(key(42), 2), partitionable
  uint32_t dk0_0, dk0_1, dk1_0, dk1_1;
  threefry2x32(0u, 42u, 0u, 0u, dk0_0, dk0_1);
  threefry2x32(0u, 42u, 0u, 1u, dk1_0, dk1_1);

  const int BLK = 256;
  const int gridN = (N_NODES + BLK - 1) / BLK;
  const int gridNF = (FEAT_TOTAL + BLK - 1) / BLK;    // wave per node
  const int gridNH = (N_NODES * 32 + BLK - 1) / BLK;  // half-wave per node
  const int gridT = (N_NODES + 63) / 64;              // 64-row gemm tiles

  // ---- build ELL (dinv fused into phaseC) + fused normw/convert ----
  hipMemsetAsync(bfill, 0, 256 * sizeof(int), stream);
  phaseA<<<NB, BLK, 0, stream>>>(row, col, ew, bfill, bkt, N_EDGES);
  phaseC<<<NB, BLK, 0, stream>>>(bfill, bkt, ell, cnt, dinv);
  normw_cvt<<<gridNF, BLK, 0, stream>>>(ell, cnt, dinv, x, W0, W1, xb, Wt0,
                                        Wt1, N_NODES);

  // ---- layer 0: xb -> F0 ----
  prop_bf16<<<gridNH, BLK, 0, stream>>>(xb, F1, ell, cnt, N_NODES);
  prop_bf16<<<gridNH, BLK, 0, stream>>>(F1, F2, ell, cnt, N_NODES);
  gemm3_mfma<<<gridT, BLK, 0, stream>>>(xb, F1, F2, Wt0, F0, N_NODES, dk0_0,
                                        dk0_1, a0);
  // ---- layer 1: F0 -> F0 (in-place safe) ----
  prop_bf16<<<gridNH, BLK, 0, stream>>>(F0, F1, ell, cnt, N_NODES);
  prop_bf16<<<gridNH, BLK, 0, stream>>>(F1, F2, ell, cnt, N_NODES);
  gemm3_mfma<<<gridT, BLK, 0, stream>>>(F0, F1, F2, Wt1, F0, N_NODES, dk1_0,
                                        dk1_1, a1);
  // ---- layer 2 (pushed-W): out = y0 + A(y1 + A y2), fp32 ----
  matvec3_bf16<<<gridNF, BLK, 0, stream>>>(F0, W2, y0, y1, y2, N_NODES);
  sprop_add_ell<<<gridN, BLK, 0, stream>>>(y2, y1, z1, ell, cnt, N_NODES);
  sprop_add_ell<<<gridN, BLK, 0, stream>>>(z1, y0, out, ell, cnt, N_NODES);
}